// Round 2
// baseline (380.761 us; speedup 1.0000x reference)
//
#include <hip/hip_runtime.h>
#include <hip/hip_bf16.h>

#define SEQ 2048
#define DM 2048
#define NH 16
#define NKV 4
#define HD 128

typedef float f32x4 __attribute__((ext_vector_type(4)));
typedef short s16x8 __attribute__((ext_vector_type(8)));
typedef short s16x4 __attribute__((ext_vector_type(4)));

__device__ inline __hip_bfloat16 f2b(float f) { return __float2bfloat16(f); }
__device__ inline float b2f_us(unsigned short u) { return __uint_as_float(((unsigned)u) << 16); }
__device__ inline short f2b_s(float f) {
    __hip_bfloat16 h = __float2bfloat16(f);
    return *(short*)&h;
}

// async global->LDS, 16B per lane; HW dest = wave-uniform base + lane*16.
__device__ inline void gl_lds16(const void* g, void* l) {
    __builtin_amdgcn_global_load_lds((const __attribute__((address_space(1))) void*)g,
                                     (__attribute__((address_space(3))) void*)l, 16, 0, 0);
}

// ---------------- cast fp32 -> bf16 ----------------
__global__ void cast_kernel(const float* __restrict__ in, __hip_bfloat16* __restrict__ out, int n) {
    int i = (blockIdx.x * 256 + threadIdx.x) * 4;
    if (i < n) {
        float4 v = *(const float4*)(in + i);
        __hip_bfloat16 o4[4] = {f2b(v.x), f2b(v.y), f2b(v.z), f2b(v.w)};
        *(ushort4*)(out + i) = *(ushort4*)o4;
    }
}

// ---------------- transpose + cast: in[K][N] fp32 -> out[N][K] bf16 ----------------
__global__ void transpose_cast(const float* __restrict__ in, __hip_bfloat16* __restrict__ out,
                               int K, int N) {
    __shared__ float tile[32][33];
    int n0 = blockIdx.x * 32, k0 = blockIdx.y * 32;
    int tx = threadIdx.x, ty = threadIdx.y; // block (32,8)
    for (int r = ty; r < 32; r += 8)
        tile[r][tx] = in[(size_t)(k0 + r) * N + n0 + tx];
    __syncthreads();
    for (int r = ty; r < 32; r += 8)
        out[(size_t)(n0 + r) * K + k0 + tx] = f2b(tile[tx][r]);
}

// ---------------- GEMM: C[M][N] = A[M][Kd] * Bt[N][Kd]^T ----------------
// m97 structure + GROUP_M=8 grouped supertile swizzle.
template <int OUT_F32>
__global__ __launch_bounds__(256, 3) void gemm_bt(
    const __hip_bfloat16* __restrict__ A,
    const __hip_bfloat16* __restrict__ Bt,
    void* __restrict__ Cp, int M, int N, int Kd) {
    __shared__ __hip_bfloat16 As[128 * 64]; // [row][64], swizzled 16B slots
    __shared__ __hip_bfloat16 Bs[128 * 64];
    const int nx = gridDim.x, ny = gridDim.y;
    const int pid = blockIdx.y * nx + blockIdx.x;
    const int GM = 8;
    const int grp = pid / (GM * nx);
    const int first = grp * GM;
    const int gsz = (ny - first < GM) ? (ny - first) : GM;
    const int mt = first + (pid % gsz);
    const int ntile = (pid % (GM * nx)) / gsz;
    const int m0 = mt * 128, n0 = ntile * 128;

    const int t = threadIdx.x;
    const int wv = t >> 6, lane = t & 63;
    const int wm = (wv >> 1) * 64, wn = (wv & 1) * 64;
    const int lrow = lane & 15, quad = lane >> 4;
    f32x4 acc[4][4];
    f32x4 z4 = {0.f, 0.f, 0.f, 0.f};
    for (int i = 0; i < 4; ++i)
        for (int j = 0; j < 4; ++j) acc[i][j] = z4;

    for (int k0 = 0; k0 < Kd; k0 += 64) {
        __syncthreads();
        for (int i = 0; i < 4; ++i) {
            int flat = i * 256 + t;          // 16B slot id
            int row = flat >> 3;
            int cb = (flat & 7) ^ (row & 7); // logical 16B-block for this slot
            gl_lds16(A + (size_t)(m0 + row) * Kd + k0 + cb * 8, &As[flat * 8]);
            gl_lds16(Bt + (size_t)(n0 + row) * Kd + k0 + cb * 8, &Bs[flat * 8]);
        }
        __syncthreads();
        for (int kk = 0; kk < 2; ++kk) {
            s16x8 af[4], bf[4];
            for (int i = 0; i < 4; ++i) {
                int ra = wm + i * 16 + lrow;
                int rb = wn + i * 16 + lrow;
                int pba = ((kk * 4 + quad) ^ (ra & 7)) * 8;
                int pbb = ((kk * 4 + quad) ^ (rb & 7)) * 8;
                af[i] = *(const s16x8*)&As[ra * 64 + pba];
                bf[i] = *(const s16x8*)&Bs[rb * 64 + pbb];
            }
            for (int i = 0; i < 4; ++i)
                for (int j = 0; j < 4; ++j)
                    acc[i][j] = __builtin_amdgcn_mfma_f32_16x16x32_bf16(af[i], bf[j],
                                                                        acc[i][j], 0, 0, 0);
        }
    }
    for (int i = 0; i < 4; ++i)
        for (int j = 0; j < 4; ++j)
            for (int r = 0; r < 4; ++r) {
                int m = m0 + wm + i * 16 + quad * 4 + r;
                int n = n0 + wn + j * 16 + lrow;
                if (OUT_F32)
                    ((float*)Cp)[(size_t)m * N + n] = acc[i][j][r];
                else
                    ((__hip_bfloat16*)Cp)[(size_t)m * N + n] = f2b(acc[i][j][r]);
            }
}

// ---------------- RoPE + reshape (q, k only), vectorized ----------------
// R9: Q is pre-scaled by softmax_scale * log2(e) so attention can run entirely
// in the exp2 domain with no per-score multiply. K is unscaled.
#define QSC 0.12751744f /* (1/sqrt(128)) * 1.4426950408889634 */
__global__ void rope_reshape(const __hip_bfloat16* __restrict__ qkv,
                             const float* __restrict__ fcos, const float* __restrict__ fsin,
                             __hip_bfloat16* __restrict__ q, __hip_bfloat16* __restrict__ k) {
    int tok = blockIdx.x; // b*SEQ + s
    int b = tok >> 11, s = tok & 2047;
    const __hip_bfloat16* row = qkv + (size_t)tok * 3072;
    for (int it = threadIdx.x; it < 320; it += 256) { // 2560 elems / 8
        int col = it * 8;
        s16x8 v = *(const s16x8*)(row + col);
        int p0 = (col & 127) >> 1;
        f32x4 c4 = *(const f32x4*)(fcos + s * 64 + p0);
        f32x4 s4 = *(const f32x4*)(fsin + s * 64 + p0);
        float scl = (col < 2048) ? QSC : 1.0f;
        short outv[8];
        for (int p = 0; p < 4; ++p) {
            float x0 = b2f_us((unsigned short)v[2 * p]);
            float x1 = b2f_us((unsigned short)v[2 * p + 1]);
            outv[2 * p] = f2b_s((x0 * c4[p] - x1 * s4[p]) * scl);
            outv[2 * p + 1] = f2b_s((x0 * s4[p] + x1 * c4[p]) * scl);
        }
        int d = col & 127;
        if (col < 2048) {
            int h = col >> 7;
            *(s16x8*)(q + ((size_t)((b * NH + h) * SEQ + s)) * HD + d) = *(s16x8*)outv;
        } else {
            int h = (col - 2048) >> 7;
            *(s16x8*)(k + ((size_t)((b * NKV + h) * SEQ + s)) * HD + d) = *(s16x8*)outv;
        }
    }
}

// ---------------- V transpose via LDS: qkv v-cols -> vt[b][kv][d][s] ----------------
__global__ void vtrans(const __hip_bfloat16* __restrict__ qkv, __hip_bfloat16* __restrict__ vt) {
    __shared__ __hip_bfloat16 tile[128][136];
    int s0 = blockIdx.x * 128;
    int bh = blockIdx.y; // b*NKV + kvh
    int b = bh >> 2, kvh = bh & 3;
    int t = threadIdx.x;
    for (int i = 0; i < 8; ++i) {
        int flat = (i * 256 + t) * 8;
        int row = flat >> 7, col = flat & 127;
        *(s16x8*)&tile[row][col] =
            *(const s16x8*)(qkv + (size_t)(b * SEQ + s0 + row) * 3072 + 2560 + kvh * 128 + col);
    }
    __syncthreads();
    for (int i = 0; i < 8; ++i) {
        int dd = i * 16 + (t >> 4);
        int ss = (t & 15) * 8;
        __hip_bfloat16 tmp[8];
        for (int j = 0; j < 8; ++j) tmp[j] = tile[ss + j][dd];
        *(s16x8*)(vt + ((size_t)((b * NKV + kvh) * HD + dd)) * SEQ + s0 + ss) = *(s16x8*)tmp;
    }
}

// ---------------- causal flash attention (GQA) ----------------
// R9 restructure for CU-level utilization (the R8 counters showed occupancy 26% of a
// 50% cap: 512 blocks = exactly 2/CU, the short co-resident block drains with no
// backfill -> modeled util 52%):
//  * 64 q-rows / 4 waves / 256 threads per block; grid (32,32) = 1024 blocks = 4/CU.
//    Every wave active in every tile (no wave_active idling).
//  * Per-y-class flip ((y>>3)&1): co-resident quads {a,a,33-a,33-a} tiles -> ~70% util.
//  * Single-buffered UNPADDED XOR-swizzled K/V LDS: 32,768 B -> 4 blocks/CU.
//    Swizzle: 16B block index ^= (row&7) (same scheme as gemm_bt; conflict-free reads).
//  * VALU cuts: Q pre-scaled by scale*log2e (exp2 domain, no per-score mul);
//    exp2f; defer-max (T13): skip accO/l rescale when __all(mt2 <= m_i + 8).
// V key-column permutation (from R8): posOf(key) lets P feed PV straight from regs.
__global__ __launch_bounds__(256, 4) void attn_kernel(
    const __hip_bfloat16* __restrict__ q, const __hip_bfloat16* __restrict__ k,
    const __hip_bfloat16* __restrict__ vt, __hip_bfloat16* __restrict__ o) {
    __shared__ __hip_bfloat16 Ks[64 * 128];  // keys x d, swizzled 16B blocks
    __shared__ __hip_bfloat16 Vs[128 * 64];  // d x keys, permuted cols + swizzled blocks

    const int bh = blockIdx.y;
    const int flip = (blockIdx.y >> 3) & 1;
    const int bx = flip ? (31 - (int)blockIdx.x) : (int)blockIdx.x;
    const int b = bh >> 4, h = bh & 15;
    const int kvh = h >> 2;
    const int t = threadIdx.x;
    const int w = t >> 6, lane = t & 63;
    const int lrow = lane & 15, quad = lane >> 4;
    const int q0 = bx * 64;
    const int qrow = q0 + w * 16 + lrow; // this lane's ONE q row (n-dim)

    // Q fragments, B-operand role: n=qrow (lrow), k=d (quad*8+j). Pre-scaled in rope.
    const __hip_bfloat16* qp = q + ((size_t)((b * NH + h) * SEQ + qrow)) * HD;
    s16x8 qf[4];
    for (int ks = 0; ks < 4; ++ks) qf[ks] = *(const s16x8*)(qp + ks * 32 + quad * 8);

    float m_i = -1e30f, l_i = 0.f;
    f32x4 accO[8];
    f32x4 z4 = {0.f, 0.f, 0.f, 0.f};
    for (int d = 0; d < 8; ++d) accO[d] = z4;

    const __hip_bfloat16* kbase = k + ((size_t)(b * NKV + kvh) * SEQ) * HD;
    const __hip_bfloat16* vbase = vt + ((size_t)(b * NKV + kvh) * HD) * SEQ;

    s16x8 kr[4], vr[4];
    auto load_tile = [&](int kt) {
        for (int i = 0; i < 4; ++i) {
            int flat = (i * 256 + t) * 8;
            kr[i] = *(const s16x8*)(kbase + (size_t)(kt * 64 + (flat >> 7)) * HD + (flat & 127));
            vr[i] = *(const s16x8*)(vbase + (size_t)(flat >> 6) * SEQ + kt * 64 + (flat & 63));
        }
    };
    auto store_tile = [&]() {
        for (int i = 0; i < 4; ++i) {
            int flat = (i * 256 + t) * 8;
            int krow = flat >> 7, kcol = flat & 127;
            *(s16x8*)&Ks[krow * 128 + (((kcol >> 3) ^ (krow & 7)) << 3)] = kr[i];
            // V: permuted key columns (posOf), then block-swizzle per d-row.
            int vrow = flat >> 6, k0 = flat & 63;
            int pb = ((k0 >> 5) << 5) | (((k0 >> 2) & 2) << 3) | (((k0 >> 4) & 1) << 2);
            int blo = pb >> 3, sub = pb & 7;
            s16x4 lo = {vr[i][0], vr[i][1], vr[i][2], vr[i][3]};
            s16x4 hi = {vr[i][4], vr[i][5], vr[i][6], vr[i][7]};
            *(s16x4*)&Vs[vrow * 64 + ((blo ^ (vrow & 7)) << 3) + sub] = lo;
            *(s16x4*)&Vs[vrow * 64 + (((blo + 1) ^ (vrow & 7)) << 3) + sub] = hi;
        }
    };

    const int nkt = bx + 1; // keys [0, q0+64)
    load_tile(0);
    store_tile();

    for (int kt = 0; kt < nkt; ++kt) {
        __syncthreads(); // LDS tile ready
        const bool more = (kt + 1) < nkt;
        if (more) load_tile(kt + 1); // global->reg, in flight under compute
        const bool dia = (kt == bx); // only the last tile touches the diagonal

        float sv[4][4];
        for (int nt = 0; nt < 4; ++nt) {
            f32x4 sacc = z4;
            const int row = nt * 16 + lrow;
            for (int ks = 0; ks < 4; ++ks) {
                s16x8 kf = *(const s16x8*)&Ks[row * 128 + (((ks * 4 + quad) ^ (lrow & 7)) << 3)];
                sacc = __builtin_amdgcn_mfma_f32_16x16x32_bf16(kf, qf[ks], sacc, 0, 0, 0);
            }
            if (dia) {
                for (int r = 0; r < 4; ++r) {
                    int key = kt * 64 + nt * 16 + quad * 4 + r;
                    sv[nt][r] = (key > qrow) ? -1e30f : sacc[r];
                }
            } else {
                for (int r = 0; r < 4; ++r) sv[nt][r] = sacc[r];
            }
        }
        float mt2 = -1e30f;
        for (int nt = 0; nt < 4; ++nt)
            for (int r = 0; r < 4; ++r) mt2 = fmaxf(mt2, sv[nt][r]);
        mt2 = fmaxf(mt2, __shfl_xor(mt2, 16, 64));
        mt2 = fmaxf(mt2, __shfl_xor(mt2, 32, 64));
        // defer-max: only rescale when the running max grew by >8 (exp2 domain,
        // so deferred p is bounded by 2^8 = 256 -- safe in f32/bf16).
        if (!__all(mt2 <= m_i + 8.f)) {
            float mn = fmaxf(m_i, mt2);
            float alpha = exp2f(m_i - mn);
            l_i *= alpha;
            for (int d = 0; d < 8; ++d)
                for (int r = 0; r < 4; ++r) accO[d][r] *= alpha;
            m_i = mn;
        }
        // P in-register; k-slot (quad,j) of PV mfma#0 <-> key (j>>2)*16+quad*4+(j&3).
        float rs = 0.f;
        s16x8 pf0, pf1;
#pragma unroll
        for (int j = 0; j < 8; ++j) {
            float p0 = exp2f(sv[j >> 2][j & 3] - m_i);
            float p1 = exp2f(sv[2 + (j >> 2)][j & 3] - m_i);
            rs += p0 + p1;
            pf0[j] = f2b_s(p0);
            pf1[j] = f2b_s(p1);
        }
        rs += __shfl_xor(rs, 16, 64);
        rs += __shfl_xor(rs, 32, 64);
        l_i += rs;
        for (int dt = 0; dt < 8; ++dt) {
            const int vrow = dt * 16 + lrow;
            s16x8 vf0 = *(const s16x8*)&Vs[vrow * 64 + ((quad ^ (lrow & 7)) << 3)];
            s16x8 vf1 = *(const s16x8*)&Vs[vrow * 64 + (((4 + quad) ^ (lrow & 7)) << 3)];
            accO[dt] = __builtin_amdgcn_mfma_f32_16x16x32_bf16(vf0, pf0, accO[dt], 0, 0, 0);
            accO[dt] = __builtin_amdgcn_mfma_f32_16x16x32_bf16(vf1, pf1, accO[dt], 0, 0, 0);
        }

        __syncthreads(); // everyone done reading this tile
        if (more) store_tile();
    }
    float inv = 1.0f / l_i;
    __hip_bfloat16* op = o + (size_t)(b * SEQ + qrow) * DM + h * HD;
    for (int dt = 0; dt < 8; ++dt) {
        short ov[4];
        for (int r = 0; r < 4; ++r) ov[r] = f2b_s(accO[dt][r] * inv);
        *(s16x4*)(op + dt * 16 + quad * 4) = *(s16x4*)ov;
    }
}

extern "C" void kernel_launch(void* const* d_in, const int* in_sizes, int n_in,
                              void* d_out, int out_size, void* d_ws, size_t ws_size,
                              hipStream_t stream) {
    (void)in_sizes; (void)n_in; (void)out_size; (void)ws_size;
    const float* x  = (const float*)d_in[0];
    const float* fc = (const float*)d_in[1];
    const float* fs = (const float*)d_in[2];
    // d_in[3] = mask: exactly causal, applied analytically
    const float* wq = (const float*)d_in[4];
    const float* wk = (const float*)d_in[5];
    const float* wv = (const float*)d_in[6];
    const float* wo = (const float*)d_in[7];

    __hip_bfloat16* xb    = (__hip_bfloat16*)d_ws;            // [4096][2048]
    __hip_bfloat16* wqkvt = xb + (size_t)8388608;             // [3072][2048]
    __hip_bfloat16* wot   = wqkvt + (size_t)6291456;          // [2048][2048]
    __hip_bfloat16* qkv   = wot + (size_t)4194304;            // [4096][3072]
    __hip_bfloat16* qb    = xb;                               // aliases xb
    __hip_bfloat16* kb    = wqkvt;                            // aliases wqkvt
    __hip_bfloat16* vtb   = wqkvt + (size_t)2097152;
    __hip_bfloat16* attno = qkv;                              // aliases qkv

    cast_kernel<<<8192, 256, 0, stream>>>(x, xb, 8388608);
    transpose_cast<<<dim3(64, 64), dim3(32, 8), 0, stream>>>(wq, wqkvt, 2048, 2048);
    transpose_cast<<<dim3(16, 64), dim3(32, 8), 0, stream>>>(wk, wqkvt + (size_t)2048 * 2048, 2048, 512);
    transpose_cast<<<dim3(16, 64), dim3(32, 8), 0, stream>>>(wv, wqkvt + (size_t)2560 * 2048, 2048, 512);
    transpose_cast<<<dim3(64, 64), dim3(32, 8), 0, stream>>>(wo, wot, 2048, 2048);
    gemm_bt<0><<<dim3(24, 32), 256, 0, stream>>>(xb, wqkvt, qkv, 4096, 3072, 2048);
    rope_reshape<<<4096, 256, 0, stream>>>(qkv, fc, fs, qb, kb);
    vtrans<<<dim3(16, 8), 256, 0, stream>>>(qkv, vtb);
    attn_kernel<<<dim3(32, 32), 256, 0, stream>>>(qb, kb, vtb, attno);
    gemm_bt<1><<<dim3(16, 32), 256, 0, stream>>>(attno, wot, d_out, 4096, 2048, 2048);
}

// Round 3
// 350.712 us; speedup vs baseline: 1.0857x; 1.0857x over previous
//
#include <hip/hip_runtime.h>
#include <hip/hip_bf16.h>

#define SEQ 2048
#define DM 2048
#define NH 16
#define NKV 4
#define HD 128

typedef float f32x4 __attribute__((ext_vector_type(4)));
typedef short s16x8 __attribute__((ext_vector_type(8)));
typedef short s16x4 __attribute__((ext_vector_type(4)));

__device__ inline __hip_bfloat16 f2b(float f) { return __float2bfloat16(f); }
__device__ inline float b2f_us(unsigned short u) { return __uint_as_float(((unsigned)u) << 16); }
__device__ inline short f2b_s(float f) {
    __hip_bfloat16 h = __float2bfloat16(f);
    return *(short*)&h;
}

// async global->LDS, 16B per lane; HW dest = wave-uniform base + lane*16.
__device__ inline void gl_lds16(const void* g, void* l) {
    __builtin_amdgcn_global_load_lds((const __attribute__((address_space(1))) void*)g,
                                     (__attribute__((address_space(3))) void*)l, 16, 0, 0);
}

// ---------------- cast fp32 -> bf16 ----------------
__global__ void cast_kernel(const float* __restrict__ in, __hip_bfloat16* __restrict__ out, int n) {
    int i = (blockIdx.x * 256 + threadIdx.x) * 4;
    if (i < n) {
        float4 v = *(const float4*)(in + i);
        __hip_bfloat16 o4[4] = {f2b(v.x), f2b(v.y), f2b(v.z), f2b(v.w)};
        *(ushort4*)(out + i) = *(ushort4*)o4;
    }
}

// ---------------- transpose + cast: in[K][N] fp32 -> out[N][K] bf16 ----------------
__global__ void transpose_cast(const float* __restrict__ in, __hip_bfloat16* __restrict__ out,
                               int K, int N) {
    __shared__ float tile[32][33];
    int n0 = blockIdx.x * 32, k0 = blockIdx.y * 32;
    int tx = threadIdx.x, ty = threadIdx.y; // block (32,8)
    for (int r = ty; r < 32; r += 8)
        tile[r][tx] = in[(size_t)(k0 + r) * N + n0 + tx];
    __syncthreads();
    for (int r = ty; r < 32; r += 8)
        out[(size_t)(n0 + r) * K + k0 + tx] = f2b(tile[tx][r]);
}

// ---------------- GEMM: C[M][N] = A[M][Kd] * Bt[N][Kd]^T ----------------
// m97 structure + GROUP_M=8 grouped supertile swizzle.
template <int OUT_F32>
__global__ __launch_bounds__(256, 3) void gemm_bt(
    const __hip_bfloat16* __restrict__ A,
    const __hip_bfloat16* __restrict__ Bt,
    void* __restrict__ Cp, int M, int N, int Kd) {
    __shared__ __hip_bfloat16 As[128 * 64]; // [row][64], swizzled 16B slots
    __shared__ __hip_bfloat16 Bs[128 * 64];
    const int nx = gridDim.x, ny = gridDim.y;
    const int pid = blockIdx.y * nx + blockIdx.x;
    const int GM = 8;
    const int grp = pid / (GM * nx);
    const int first = grp * GM;
    const int gsz = (ny - first < GM) ? (ny - first) : GM;
    const int mt = first + (pid % gsz);
    const int ntile = (pid % (GM * nx)) / gsz;
    const int m0 = mt * 128, n0 = ntile * 128;

    const int t = threadIdx.x;
    const int wv = t >> 6, lane = t & 63;
    const int wm = (wv >> 1) * 64, wn = (wv & 1) * 64;
    const int lrow = lane & 15, quad = lane >> 4;
    f32x4 acc[4][4];
    f32x4 z4 = {0.f, 0.f, 0.f, 0.f};
    for (int i = 0; i < 4; ++i)
        for (int j = 0; j < 4; ++j) acc[i][j] = z4;

    for (int k0 = 0; k0 < Kd; k0 += 64) {
        __syncthreads();
        for (int i = 0; i < 4; ++i) {
            int flat = i * 256 + t;          // 16B slot id
            int row = flat >> 3;
            int cb = (flat & 7) ^ (row & 7); // logical 16B-block for this slot
            gl_lds16(A + (size_t)(m0 + row) * Kd + k0 + cb * 8, &As[flat * 8]);
            gl_lds16(Bt + (size_t)(n0 + row) * Kd + k0 + cb * 8, &Bs[flat * 8]);
        }
        __syncthreads();
        for (int kk = 0; kk < 2; ++kk) {
            s16x8 af[4], bf[4];
            for (int i = 0; i < 4; ++i) {
                int ra = wm + i * 16 + lrow;
                int rb = wn + i * 16 + lrow;
                int pba = ((kk * 4 + quad) ^ (ra & 7)) * 8;
                int pbb = ((kk * 4 + quad) ^ (rb & 7)) * 8;
                af[i] = *(const s16x8*)&As[ra * 64 + pba];
                bf[i] = *(const s16x8*)&Bs[rb * 64 + pbb];
            }
            for (int i = 0; i < 4; ++i)
                for (int j = 0; j < 4; ++j)
                    acc[i][j] = __builtin_amdgcn_mfma_f32_16x16x32_bf16(af[i], bf[j],
                                                                        acc[i][j], 0, 0, 0);
        }
    }
    for (int i = 0; i < 4; ++i)
        for (int j = 0; j < 4; ++j)
            for (int r = 0; r < 4; ++r) {
                int m = m0 + wm + i * 16 + quad * 4 + r;
                int n = n0 + wn + j * 16 + lrow;
                if (OUT_F32)
                    ((float*)Cp)[(size_t)m * N + n] = acc[i][j][r];
                else
                    ((__hip_bfloat16*)Cp)[(size_t)m * N + n] = f2b(acc[i][j][r]);
            }
}

// ---------------- RoPE + reshape (q, k only), vectorized ----------------
// Q is pre-scaled by softmax_scale * log2(e) so attention runs in the exp2 domain
// with no per-score multiply. K is unscaled.
#define QSC 0.12751744f /* (1/sqrt(128)) * 1.4426950408889634 */
__global__ void rope_reshape(const __hip_bfloat16* __restrict__ qkv,
                             const float* __restrict__ fcos, const float* __restrict__ fsin,
                             __hip_bfloat16* __restrict__ q, __hip_bfloat16* __restrict__ k) {
    int tok = blockIdx.x; // b*SEQ + s
    int b = tok >> 11, s = tok & 2047;
    const __hip_bfloat16* row = qkv + (size_t)tok * 3072;
    for (int it = threadIdx.x; it < 320; it += 256) { // 2560 elems / 8
        int col = it * 8;
        s16x8 v = *(const s16x8*)(row + col);
        int p0 = (col & 127) >> 1;
        f32x4 c4 = *(const f32x4*)(fcos + s * 64 + p0);
        f32x4 s4 = *(const f32x4*)(fsin + s * 64 + p0);
        float scl = (col < 2048) ? QSC : 1.0f;
        short outv[8];
        for (int p = 0; p < 4; ++p) {
            float x0 = b2f_us((unsigned short)v[2 * p]);
            float x1 = b2f_us((unsigned short)v[2 * p + 1]);
            outv[2 * p] = f2b_s((x0 * c4[p] - x1 * s4[p]) * scl);
            outv[2 * p + 1] = f2b_s((x0 * s4[p] + x1 * c4[p]) * scl);
        }
        int d = col & 127;
        if (col < 2048) {
            int h = col >> 7;
            *(s16x8*)(q + ((size_t)((b * NH + h) * SEQ + s)) * HD + d) = *(s16x8*)outv;
        } else {
            int h = (col - 2048) >> 7;
            *(s16x8*)(k + ((size_t)((b * NKV + h) * SEQ + s)) * HD + d) = *(s16x8*)outv;
        }
    }
}

// ---------------- V transpose via LDS: qkv v-cols -> vt[b][kv][d][s] ----------------
__global__ void vtrans(const __hip_bfloat16* __restrict__ qkv, __hip_bfloat16* __restrict__ vt) {
    __shared__ __hip_bfloat16 tile[128][136];
    int s0 = blockIdx.x * 128;
    int bh = blockIdx.y; // b*NKV + kvh
    int b = bh >> 2, kvh = bh & 3;
    int t = threadIdx.x;
    for (int i = 0; i < 8; ++i) {
        int flat = (i * 256 + t) * 8;
        int row = flat >> 7, col = flat & 127;
        *(s16x8*)&tile[row][col] =
            *(const s16x8*)(qkv + (size_t)(b * SEQ + s0 + row) * 3072 + 2560 + kvh * 128 + col);
    }
    __syncthreads();
    for (int i = 0; i < 8; ++i) {
        int dd = i * 16 + (t >> 4);
        int ss = (t & 15) * 8;
        __hip_bfloat16 tmp[8];
        for (int j = 0; j < 8; ++j) tmp[j] = tile[ss + j][dd];
        *(s16x8*)(vt + ((size_t)((b * NKV + kvh) * HD + dd)) * SEQ + s0 + ss) = *(s16x8*)tmp;
    }
}

// ---------------- causal flash attention (GQA) ----------------
// R10: R9 structure with the spill fixed (R9's WRITE_SIZE=140MB was scratch traffic:
// kr[4]+vr[4] staging pushed the live set past launch_bounds(256,4)'s 128-reg cap).
//  * K staged via global_load_lds with PRE-SWIZZLED per-lane source (m173 pattern,
//    same as gemm_bt) -> zero staging regs for K. K is double-buffered; glK(kt+1) is
//    issued right after the top barrier so its latency hides under tile kt's compute.
//  * V stays reg-staged (posOf permute isn't lane-linear-16B), only 16 live regs.
//  * __launch_bounds__(256,3): cap ~170 regs -> no spill; 3 blocks/CU (LDS 48KB).
// Kept from R9: 64 q-rows/4 waves, grid (32,32), per-y-class flip for balanced
// co-resident drain, exp2-domain softmax on pre-scaled Q, defer-max (T13),
// XOR-swizzled K/V LDS, V key-column posOf permutation (P feeds PV from regs).
__global__ __launch_bounds__(256, 3) void attn_kernel(
    const __hip_bfloat16* __restrict__ q, const __hip_bfloat16* __restrict__ k,
    const __hip_bfloat16* __restrict__ vt, __hip_bfloat16* __restrict__ o) {
    __shared__ __hip_bfloat16 Ks[2][64 * 128]; // keys x d, swizzled 16B blocks, dbuf
    __shared__ __hip_bfloat16 Vs[128 * 64];    // d x keys, permuted cols + swizzled

    const int bh = blockIdx.y;
    const int flip = (blockIdx.y >> 3) & 1;
    const int bx = flip ? (31 - (int)blockIdx.x) : (int)blockIdx.x;
    const int b = bh >> 4, h = bh & 15;
    const int kvh = h >> 2;
    const int t = threadIdx.x;
    const int lane = t & 63;
    const int lrow = lane & 15, quad = lane >> 4;
    const int q0 = bx * 64;
    const int w = t >> 6;
    const int qrow = q0 + w * 16 + lrow; // this lane's ONE q row (n-dim)

    // Q fragments, B-operand role: n=qrow (lrow), k=d (quad*8+j). Pre-scaled in rope.
    const __hip_bfloat16* qp = q + ((size_t)((b * NH + h) * SEQ + qrow)) * HD;
    s16x8 qf[4];
    for (int ks = 0; ks < 4; ++ks) qf[ks] = *(const s16x8*)(qp + ks * 32 + quad * 8);

    float m_i = -1e30f, l_i = 0.f;
    f32x4 accO[8];
    f32x4 z4 = {0.f, 0.f, 0.f, 0.f};
    for (int d = 0; d < 8; ++d) accO[d] = z4;

    const __hip_bfloat16* kbase = k + ((size_t)(b * NKV + kvh) * SEQ) * HD;
    const __hip_bfloat16* vbase = vt + ((size_t)(b * NKV + kvh) * HD) * SEQ;

    // Per-lane pre-swizzled K source: LDS slot (krow, b') receives global block
    // b = b' ^ (krow&7). krow = i*16 + (t>>4), b' = t&15 -> i-independent lane term.
    const __hip_bfloat16* ksrc0 =
        kbase + (t >> 4) * HD + (((t & 15) ^ ((t >> 4) & 7)) << 3);
    auto issue_k = [&](int kt, int bsel) {
        const __hip_bfloat16* src = ksrc0 + (size_t)kt * 64 * HD;
        for (int i = 0; i < 4; ++i)
            gl_lds16(src + i * 16 * HD, &Ks[bsel][(i * 256 + t) * 8]);
    };

    s16x8 vr[4];
    auto load_v = [&](int kt) {
        for (int i = 0; i < 4; ++i) {
            int flat = (i * 256 + t) * 8;
            vr[i] = *(const s16x8*)(vbase + (size_t)(flat >> 6) * SEQ + kt * 64 + (flat & 63));
        }
    };
    auto store_v = [&]() {
        for (int i = 0; i < 4; ++i) {
            int flat = (i * 256 + t) * 8;
            int vrow = flat >> 6, k0 = flat & 63;
            int pb = ((k0 >> 5) << 5) | (((k0 >> 2) & 2) << 3) | (((k0 >> 4) & 1) << 2);
            int blo = pb >> 3, sub = pb & 7;
            s16x4 lo = {vr[i][0], vr[i][1], vr[i][2], vr[i][3]};
            s16x4 hi = {vr[i][4], vr[i][5], vr[i][6], vr[i][7]};
            *(s16x4*)&Vs[vrow * 64 + ((blo ^ (vrow & 7)) << 3) + sub] = lo;
            *(s16x4*)&Vs[vrow * 64 + (((blo + 1) ^ (vrow & 7)) << 3) + sub] = hi;
        }
    };

    const int nkt = bx + 1; // keys [0, q0+64)
    issue_k(0, 0);
    load_v(0);
    store_v();

    for (int kt = 0; kt < nkt; ++kt) {
        const int cur = kt & 1;
        __syncthreads(); // Ks[cur] drained (vmcnt), Vs stores visible
        const bool more = (kt + 1) < nkt;
        if (more) {
            issue_k(kt + 1, 1 - cur); // async, hidden under this tile's compute
            load_v(kt + 1);           // global->reg prefetch
        }
        const bool dia = (kt == bx); // only the last tile touches the diagonal

        float sv[4][4];
        for (int nt = 0; nt < 4; ++nt) {
            f32x4 sacc = z4;
            const int row = nt * 16 + lrow;
            for (int ks = 0; ks < 4; ++ks) {
                s16x8 kf =
                    *(const s16x8*)&Ks[cur][row * 128 + (((ks * 4 + quad) ^ (lrow & 7)) << 3)];
                sacc = __builtin_amdgcn_mfma_f32_16x16x32_bf16(kf, qf[ks], sacc, 0, 0, 0);
            }
            if (dia) {
                for (int r = 0; r < 4; ++r) {
                    int key = kt * 64 + nt * 16 + quad * 4 + r;
                    sv[nt][r] = (key > qrow) ? -1e30f : sacc[r];
                }
            } else {
                for (int r = 0; r < 4; ++r) sv[nt][r] = sacc[r];
            }
        }
        float mt2 = -1e30f;
        for (int nt = 0; nt < 4; ++nt)
            for (int r = 0; r < 4; ++r) mt2 = fmaxf(mt2, sv[nt][r]);
        mt2 = fmaxf(mt2, __shfl_xor(mt2, 16, 64));
        mt2 = fmaxf(mt2, __shfl_xor(mt2, 32, 64));
        // defer-max: only rescale when the running max grew by >8 (exp2 domain,
        // deferred p bounded by 2^8 -- safe in f32/bf16).
        if (!__all(mt2 <= m_i + 8.f)) {
            float mn = fmaxf(m_i, mt2);
            float alpha = exp2f(m_i - mn);
            l_i *= alpha;
            for (int d = 0; d < 8; ++d)
                for (int r = 0; r < 4; ++r) accO[d][r] *= alpha;
            m_i = mn;
        }
        // P in-register; k-slot (quad,j) of PV mfma#0 <-> key (j>>2)*16+quad*4+(j&3).
        float rs = 0.f;
        s16x8 pf0, pf1;
#pragma unroll
        for (int j = 0; j < 8; ++j) {
            float p0 = exp2f(sv[j >> 2][j & 3] - m_i);
            float p1 = exp2f(sv[2 + (j >> 2)][j & 3] - m_i);
            rs += p0 + p1;
            pf0[j] = f2b_s(p0);
            pf1[j] = f2b_s(p1);
        }
        rs += __shfl_xor(rs, 16, 64);
        rs += __shfl_xor(rs, 32, 64);
        l_i += rs;
        for (int dt = 0; dt < 8; ++dt) {
            const int vrow = dt * 16 + lrow;
            s16x8 vf0 = *(const s16x8*)&Vs[vrow * 64 + ((quad ^ (lrow & 7)) << 3)];
            s16x8 vf1 = *(const s16x8*)&Vs[vrow * 64 + (((4 + quad) ^ (lrow & 7)) << 3)];
            accO[dt] = __builtin_amdgcn_mfma_f32_16x16x32_bf16(vf0, pf0, accO[dt], 0, 0, 0);
            accO[dt] = __builtin_amdgcn_mfma_f32_16x16x32_bf16(vf1, pf1, accO[dt], 0, 0, 0);
        }

        __syncthreads(); // everyone done reading Vs (and Ks[cur])
        if (more) store_v();
    }
    float inv = 1.0f / l_i;
    __hip_bfloat16* op = o + (size_t)(b * SEQ + qrow) * DM + h * HD;
    for (int dt = 0; dt < 8; ++dt) {
        short ov[4];
        for (int r = 0; r < 4; ++r) ov[r] = f2b_s(accO[dt][r] * inv);
        *(s16x4*)(op + dt * 16 + quad * 4) = *(s16x4*)ov;
    }
}

extern "C" void kernel_launch(void* const* d_in, const int* in_sizes, int n_in,
                              void* d_out, int out_size, void* d_ws, size_t ws_size,
                              hipStream_t stream) {
    (void)in_sizes; (void)n_in; (void)out_size; (void)ws_size;
    const float* x  = (const float*)d_in[0];
    const float* fc = (const float*)d_in[1];
    const float* fs = (const float*)d_in[2];
    // d_in[3] = mask: exactly causal, applied analytically
    const float* wq = (const float*)d_in[4];
    const float* wk = (const float*)d_in[5];
    const float* wv = (const float*)d_in[6];
    const float* wo = (const float*)d_in[7];

    __hip_bfloat16* xb    = (__hip_bfloat16*)d_ws;            // [4096][2048]
    __hip_bfloat16* wqkvt = xb + (size_t)8388608;             // [3072][2048]
    __hip_bfloat16* wot   = wqkvt + (size_t)6291456;          // [2048][2048]
    __hip_bfloat16* qkv   = wot + (size_t)4194304;            // [4096][3072]
    __hip_bfloat16* qb    = xb;                               // aliases xb
    __hip_bfloat16* kb    = wqkvt;                            // aliases wqkvt
    __hip_bfloat16* vtb   = wqkvt + (size_t)2097152;
    __hip_bfloat16* attno = qkv;                              // aliases qkv

    cast_kernel<<<8192, 256, 0, stream>>>(x, xb, 8388608);
    transpose_cast<<<dim3(64, 64), dim3(32, 8), 0, stream>>>(wq, wqkvt, 2048, 2048);
    transpose_cast<<<dim3(16, 64), dim3(32, 8), 0, stream>>>(wk, wqkvt + (size_t)2048 * 2048, 2048, 512);
    transpose_cast<<<dim3(16, 64), dim3(32, 8), 0, stream>>>(wv, wqkvt + (size_t)2560 * 2048, 2048, 512);
    transpose_cast<<<dim3(64, 64), dim3(32, 8), 0, stream>>>(wo, wot, 2048, 2048);
    gemm_bt<0><<<dim3(24, 32), 256, 0, stream>>>(xb, wqkvt, qkv, 4096, 3072, 2048);
    rope_reshape<<<4096, 256, 0, stream>>>(qkv, fc, fs, qb, kb);
    vtrans<<<dim3(16, 8), 256, 0, stream>>>(qkv, vtb);
    attn_kernel<<<dim3(32, 32), 256, 0, stream>>>(qb, kb, vtb, attno);
    gemm_bt<1><<<dim3(16, 32), 256, 0, stream>>>(attno, wot, d_out, 4096, 2048, 2048);
}

// Round 4
// 320.433 us; speedup vs baseline: 1.1883x; 1.0945x over previous
//
#include <hip/hip_runtime.h>
#include <hip/hip_bf16.h>

#define SEQ 2048
#define DM 2048
#define NH 16
#define NKV 4
#define HD 128

typedef float f32x4 __attribute__((ext_vector_type(4)));
typedef short s16x8 __attribute__((ext_vector_type(8)));
typedef short s16x4 __attribute__((ext_vector_type(4)));

__device__ inline __hip_bfloat16 f2b(float f) { return __float2bfloat16(f); }
__device__ inline float b2f_us(unsigned short u) { return __uint_as_float(((unsigned)u) << 16); }
__device__ inline short f2b_s(float f) {
    __hip_bfloat16 h = __float2bfloat16(f);
    return *(short*)&h;
}

// async global->LDS, 16B per lane; HW dest = wave-uniform base + lane*16.
__device__ inline void gl_lds16(const void* g, void* l) {
    __builtin_amdgcn_global_load_lds((const __attribute__((address_space(1))) void*)g,
                                     (__attribute__((address_space(3))) void*)l, 16, 0, 0);
}

// ---------------- cast fp32 -> bf16 ----------------
__global__ void cast_kernel(const float* __restrict__ in, __hip_bfloat16* __restrict__ out, int n) {
    int i = (blockIdx.x * 256 + threadIdx.x) * 4;
    if (i < n) {
        float4 v = *(const float4*)(in + i);
        __hip_bfloat16 o4[4] = {f2b(v.x), f2b(v.y), f2b(v.z), f2b(v.w)};
        *(ushort4*)(out + i) = *(ushort4*)o4;
    }
}

// ---------------- transpose + cast: in[K][N] fp32 -> out[N][K] bf16 ----------------
__global__ void transpose_cast(const float* __restrict__ in, __hip_bfloat16* __restrict__ out,
                               int K, int N) {
    __shared__ float tile[32][33];
    int n0 = blockIdx.x * 32, k0 = blockIdx.y * 32;
    int tx = threadIdx.x, ty = threadIdx.y; // block (32,8)
    for (int r = ty; r < 32; r += 8)
        tile[r][tx] = in[(size_t)(k0 + r) * N + n0 + tx];
    __syncthreads();
    for (int r = ty; r < 32; r += 8)
        out[(size_t)(n0 + r) * K + k0 + tx] = f2b(tile[tx][r]);
}

// ---------------- GEMM: C[M][N] = A[M][Kd] * Bt[N][Kd]^T ----------------
// m97 structure + GROUP_M=8 grouped supertile swizzle.
template <int OUT_F32>
__global__ __launch_bounds__(256, 3) void gemm_bt(
    const __hip_bfloat16* __restrict__ A,
    const __hip_bfloat16* __restrict__ Bt,
    void* __restrict__ Cp, int M, int N, int Kd) {
    __shared__ __hip_bfloat16 As[128 * 64]; // [row][64], swizzled 16B slots
    __shared__ __hip_bfloat16 Bs[128 * 64];
    const int nx = gridDim.x, ny = gridDim.y;
    const int pid = blockIdx.y * nx + blockIdx.x;
    const int GM = 8;
    const int grp = pid / (GM * nx);
    const int first = grp * GM;
    const int gsz = (ny - first < GM) ? (ny - first) : GM;
    const int mt = first + (pid % gsz);
    const int ntile = (pid % (GM * nx)) / gsz;
    const int m0 = mt * 128, n0 = ntile * 128;

    const int t = threadIdx.x;
    const int wv = t >> 6, lane = t & 63;
    const int wm = (wv >> 1) * 64, wn = (wv & 1) * 64;
    const int lrow = lane & 15, quad = lane >> 4;
    f32x4 acc[4][4];
    f32x4 z4 = {0.f, 0.f, 0.f, 0.f};
    for (int i = 0; i < 4; ++i)
        for (int j = 0; j < 4; ++j) acc[i][j] = z4;

    for (int k0 = 0; k0 < Kd; k0 += 64) {
        __syncthreads();
        for (int i = 0; i < 4; ++i) {
            int flat = i * 256 + t;          // 16B slot id
            int row = flat >> 3;
            int cb = (flat & 7) ^ (row & 7); // logical 16B-block for this slot
            gl_lds16(A + (size_t)(m0 + row) * Kd + k0 + cb * 8, &As[flat * 8]);
            gl_lds16(Bt + (size_t)(n0 + row) * Kd + k0 + cb * 8, &Bs[flat * 8]);
        }
        __syncthreads();
        for (int kk = 0; kk < 2; ++kk) {
            s16x8 af[4], bf[4];
            for (int i = 0; i < 4; ++i) {
                int ra = wm + i * 16 + lrow;
                int rb = wn + i * 16 + lrow;
                int pba = ((kk * 4 + quad) ^ (ra & 7)) * 8;
                int pbb = ((kk * 4 + quad) ^ (rb & 7)) * 8;
                af[i] = *(const s16x8*)&As[ra * 64 + pba];
                bf[i] = *(const s16x8*)&Bs[rb * 64 + pbb];
            }
            for (int i = 0; i < 4; ++i)
                for (int j = 0; j < 4; ++j)
                    acc[i][j] = __builtin_amdgcn_mfma_f32_16x16x32_bf16(af[i], bf[j],
                                                                        acc[i][j], 0, 0, 0);
        }
    }
    for (int i = 0; i < 4; ++i)
        for (int j = 0; j < 4; ++j)
            for (int r = 0; r < 4; ++r) {
                int m = m0 + wm + i * 16 + quad * 4 + r;
                int n = n0 + wn + j * 16 + lrow;
                if (OUT_F32)
                    ((float*)Cp)[(size_t)m * N + n] = acc[i][j][r];
                else
                    ((__hip_bfloat16*)Cp)[(size_t)m * N + n] = f2b(acc[i][j][r]);
            }
}

// ---------------- RoPE + reshape (q, k only), vectorized ----------------
// Q is pre-scaled by softmax_scale * log2(e) so attention runs in the exp2 domain
// with no per-score multiply. K is unscaled. (Verified in R9/R10: absmax unchanged.)
#define QSC 0.12751744f /* (1/sqrt(128)) * 1.4426950408889634 */
__global__ void rope_reshape(const __hip_bfloat16* __restrict__ qkv,
                             const float* __restrict__ fcos, const float* __restrict__ fsin,
                             __hip_bfloat16* __restrict__ q, __hip_bfloat16* __restrict__ k) {
    int tok = blockIdx.x; // b*SEQ + s
    int b = tok >> 11, s = tok & 2047;
    const __hip_bfloat16* row = qkv + (size_t)tok * 3072;
    for (int it = threadIdx.x; it < 320; it += 256) { // 2560 elems / 8
        int col = it * 8;
        s16x8 v = *(const s16x8*)(row + col);
        int p0 = (col & 127) >> 1;
        f32x4 c4 = *(const f32x4*)(fcos + s * 64 + p0);
        f32x4 s4 = *(const f32x4*)(fsin + s * 64 + p0);
        float scl = (col < 2048) ? QSC : 1.0f;
        short outv[8];
        for (int p = 0; p < 4; ++p) {
            float x0 = b2f_us((unsigned short)v[2 * p]);
            float x1 = b2f_us((unsigned short)v[2 * p + 1]);
            outv[2 * p] = f2b_s((x0 * c4[p] - x1 * s4[p]) * scl);
            outv[2 * p + 1] = f2b_s((x0 * s4[p] + x1 * c4[p]) * scl);
        }
        int d = col & 127;
        if (col < 2048) {
            int h = col >> 7;
            *(s16x8*)(q + ((size_t)((b * NH + h) * SEQ + s)) * HD + d) = *(s16x8*)outv;
        } else {
            int h = (col - 2048) >> 7;
            *(s16x8*)(k + ((size_t)((b * NKV + h) * SEQ + s)) * HD + d) = *(s16x8*)outv;
        }
    }
}

// ---------------- V transpose via LDS: qkv v-cols -> vt[b][kv][d][s] ----------------
__global__ void vtrans(const __hip_bfloat16* __restrict__ qkv, __hip_bfloat16* __restrict__ vt) {
    __shared__ __hip_bfloat16 tile[128][136];
    int s0 = blockIdx.x * 128;
    int bh = blockIdx.y; // b*NKV + kvh
    int b = bh >> 2, kvh = bh & 3;
    int t = threadIdx.x;
    for (int i = 0; i < 8; ++i) {
        int flat = (i * 256 + t) * 8;
        int row = flat >> 7, col = flat & 127;
        *(s16x8*)&tile[row][col] =
            *(const s16x8*)(qkv + (size_t)(b * SEQ + s0 + row) * 3072 + 2560 + kvh * 128 + col);
    }
    __syncthreads();
    for (int i = 0; i < 8; ++i) {
        int dd = i * 16 + (t >> 4);
        int ss = (t & 15) * 8;
        __hip_bfloat16 tmp[8];
        for (int j = 0; j < 8; ++j) tmp[j] = tile[ss + j][dd];
        *(s16x8*)(vt + ((size_t)((b * NKV + kvh) * HD + dd)) * SEQ + s0 + ss) = *(s16x8*)tmp;
    }
}

// ---------------- causal flash attention (GQA), 128 q-rows / 512 threads ----------------
// R11 = R8 structure (best measured: 80.5us) + orthogonal VALU cuts only.
// R8 base: no Ps LDS round-trip (V key-column posOf permute lets P feed PV from regs),
//          K/V double-buffered (one barrier/tile steady-state), reg-staged K/V,
//          anti-correlated q-tile mapping (co-resident pairs sum to 34 steps).
// R11 adds (each verified correct in R9/R10, absmax unchanged):
//  * exp2-domain softmax on pre-scaled Q (no per-score mul; exp2f not expf)
//  * defer-max (T13): skip accO/l rescale when __all(mt2 <= m_i + 8)
//  * T5 s_setprio(1/0) around the QK and PV MFMA clusters
// The R9/R10 64-row restructure measured WORSE (100-132us) and is abandoned.
__global__ __launch_bounds__(512, 4) void attn_kernel(
    const __hip_bfloat16* __restrict__ q, const __hip_bfloat16* __restrict__ k,
    const __hip_bfloat16* __restrict__ vt, __hip_bfloat16* __restrict__ o) {
    __shared__ __hip_bfloat16 Ks[2][64][136];  // keys x d, double-buffered
    __shared__ __hip_bfloat16 Vs[2][128][72];  // d x keys (key columns permuted by posOf)

    const int bh = blockIdx.y;
    const int bx = (bh < 16) ? (int)(gridDim.x - 1 - blockIdx.x) : (int)blockIdx.x;
    const int b = bh >> 4, h = bh & 15;
    const int kvh = h >> 2;
    const int t = threadIdx.x;
    const int w = t >> 6, lane = t & 63;
    const int lrow = lane & 15, quad = lane >> 4;
    const int q0 = bx * 128;
    const int qrow = q0 + w * 16 + lrow; // this lane's ONE q row (n-dim)

    // Q fragments, B-operand role: n=qrow (lrow), k=d (quad*8+j). Pre-scaled in rope.
    const __hip_bfloat16* qp = q + ((size_t)((b * NH + h) * SEQ + qrow)) * HD;
    s16x8 qf[4];
    for (int ks = 0; ks < 4; ++ks) qf[ks] = *(const s16x8*)(qp + ks * 32 + quad * 8);

    float m_i = -1e30f, l_i = 0.f;
    f32x4 accO[8];
    f32x4 z4 = {0.f, 0.f, 0.f, 0.f};
    for (int d = 0; d < 8; ++d) accO[d] = z4;

    const __hip_bfloat16* kbase = k + ((size_t)(b * NKV + kvh) * SEQ) * HD;
    const __hip_bfloat16* vbase = vt + ((size_t)(b * NKV + kvh) * HD) * SEQ;

    s16x8 kr[2], vr[2];
    auto load_tile = [&](int kt) {
        for (int i = 0; i < 2; ++i) {
            int flat = (i * 512 + t) * 8;
            kr[i] = *(const s16x8*)(kbase + (size_t)(kt * 64 + (flat >> 7)) * HD + (flat & 127));
            vr[i] = *(const s16x8*)(vbase + (size_t)(flat >> 6) * SEQ + kt * 64 + (flat & 63));
        }
    };
    auto store_tile = [&](int bsel) {
        for (int i = 0; i < 2; ++i) {
            int flat = (i * 512 + t) * 8;
            *(s16x8*)&Ks[bsel][flat >> 7][flat & 127] = kr[i];
            // V: permuted key columns. Lane holds keys k0..k0+7 (k0 = 8-aligned);
            // they land at posOf base..base+3 and base+8..base+11.
            int row = flat >> 6, k0 = flat & 63;
            int pb = ((k0 >> 5) << 5) | (((k0 >> 2) & 2) << 3) | (((k0 >> 4) & 1) << 2);
            s16x4 lo = {vr[i][0], vr[i][1], vr[i][2], vr[i][3]};
            s16x4 hi = {vr[i][4], vr[i][5], vr[i][6], vr[i][7]};
            *(s16x4*)&Vs[bsel][row][pb] = lo;
            *(s16x4*)&Vs[bsel][row][pb + 8] = hi;
        }
    };

    const int nkt = 2 * bx + 2; // keys [0, q0+128)
    load_tile(0);
    store_tile(0);

    for (int kt = 0; kt < nkt; ++kt) {
        const int cur = kt & 1;
        bool more = (kt + 1) < nkt;
        __syncthreads(); // buf[cur] ready (stored last iter / prologue)
        if (more) load_tile(kt + 1); // global->reg, hidden under compute
        bool wave_active = (kt * 64 <= q0 + w * 16 + 15);
        bool mtile = (kt >= 2 * bx); // tile may touch the diagonal

        if (wave_active) {
            float sv[4][4];
            __builtin_amdgcn_s_setprio(1);
            for (int nt = 0; nt < 4; ++nt) {
                f32x4 sacc = z4;
                for (int ks = 0; ks < 4; ++ks) {
                    s16x8 kf = *(const s16x8*)&Ks[cur][nt * 16 + lrow][ks * 32 + quad * 8];
                    sacc = __builtin_amdgcn_mfma_f32_16x16x32_bf16(kf, qf[ks], sacc, 0, 0, 0);
                }
                if (mtile) {
                    for (int r = 0; r < 4; ++r) {
                        int key = kt * 64 + nt * 16 + quad * 4 + r;
                        sv[nt][r] = (key > qrow) ? -1e30f : sacc[r];
                    }
                } else {
                    for (int r = 0; r < 4; ++r) sv[nt][r] = sacc[r];
                }
            }
            __builtin_amdgcn_s_setprio(0);
            float mt2 = fmaxf(fmaxf(fmaxf(sv[0][0], sv[0][1]), fmaxf(sv[0][2], sv[0][3])),
                              fmaxf(fmaxf(sv[1][0], sv[1][1]), fmaxf(sv[1][2], sv[1][3])));
            mt2 = fmaxf(mt2,
                        fmaxf(fmaxf(fmaxf(sv[2][0], sv[2][1]), fmaxf(sv[2][2], sv[2][3])),
                              fmaxf(fmaxf(sv[3][0], sv[3][1]), fmaxf(sv[3][2], sv[3][3]))));
            mt2 = fmaxf(mt2, __shfl_xor(mt2, 16, 64));
            mt2 = fmaxf(mt2, __shfl_xor(mt2, 32, 64));
            // defer-max: only rescale when the running max grew by >8 (exp2 domain,
            // deferred p bounded by 2^8 -- safe in f32/bf16).
            if (!__all(mt2 <= m_i + 8.f)) {
                float mn = fmaxf(m_i, mt2);
                float alpha = exp2f(m_i - mn);
                l_i *= alpha;
                for (int d = 0; d < 8; ++d)
                    for (int r = 0; r < 4; ++r) accO[d][r] *= alpha;
                m_i = mn;
            }
            // P built fully in-register; k-slot (quad,j) of PV mfma#0 is permuted
            // position quad*8+j  <->  key (j>>2)*16 + quad*4 + (j&3) = sv[j>>2][j&3].
            float rs = 0.f;
            s16x8 pf0, pf1;
#pragma unroll
            for (int j = 0; j < 8; ++j) {
                float p0 = exp2f(sv[j >> 2][j & 3] - m_i);
                float p1 = exp2f(sv[2 + (j >> 2)][j & 3] - m_i);
                rs += p0 + p1;
                pf0[j] = f2b_s(p0);
                pf1[j] = f2b_s(p1);
            }
            rs += __shfl_xor(rs, 16, 64);
            rs += __shfl_xor(rs, 32, 64);
            l_i += rs;
            __builtin_amdgcn_s_setprio(1);
            for (int dt = 0; dt < 8; ++dt) {
                s16x8 vf0 = *(const s16x8*)&Vs[cur][dt * 16 + lrow][quad * 8];
                s16x8 vf1 = *(const s16x8*)&Vs[cur][dt * 16 + lrow][32 + quad * 8];
                accO[dt] = __builtin_amdgcn_mfma_f32_16x16x32_bf16(vf0, pf0, accO[dt], 0, 0, 0);
                accO[dt] = __builtin_amdgcn_mfma_f32_16x16x32_bf16(vf1, pf1, accO[dt], 0, 0, 0);
            }
            __builtin_amdgcn_s_setprio(0);
        }

        if (more) store_tile(1 - cur); // write buffer nobody reads this iter
    }
    float inv = 1.0f / l_i;
    __hip_bfloat16* op = o + (size_t)(b * SEQ + qrow) * DM + h * HD;
    for (int dt = 0; dt < 8; ++dt) {
        short ov[4];
        for (int r = 0; r < 4; ++r) ov[r] = f2b_s(accO[dt][r] * inv);
        *(s16x4*)(op + dt * 16 + quad * 4) = *(s16x4*)ov;
    }
}

extern "C" void kernel_launch(void* const* d_in, const int* in_sizes, int n_in,
                              void* d_out, int out_size, void* d_ws, size_t ws_size,
                              hipStream_t stream) {
    (void)in_sizes; (void)n_in; (void)out_size; (void)ws_size;
    const float* x  = (const float*)d_in[0];
    const float* fc = (const float*)d_in[1];
    const float* fs = (const float*)d_in[2];
    // d_in[3] = mask: exactly causal, applied analytically
    const float* wq = (const float*)d_in[4];
    const float* wk = (const float*)d_in[5];
    const float* wv = (const float*)d_in[6];
    const float* wo = (const float*)d_in[7];

    __hip_bfloat16* xb    = (__hip_bfloat16*)d_ws;            // [4096][2048]
    __hip_bfloat16* wqkvt = xb + (size_t)8388608;             // [3072][2048]
    __hip_bfloat16* wot   = wqkvt + (size_t)6291456;          // [2048][2048]
    __hip_bfloat16* qkv   = wot + (size_t)4194304;            // [4096][3072]
    __hip_bfloat16* qb    = xb;                               // aliases xb
    __hip_bfloat16* kb    = wqkvt;                            // aliases wqkvt
    __hip_bfloat16* vtb   = wqkvt + (size_t)2097152;
    __hip_bfloat16* attno = qkv;                              // aliases qkv

    cast_kernel<<<8192, 256, 0, stream>>>(x, xb, 8388608);
    transpose_cast<<<dim3(64, 64), dim3(32, 8), 0, stream>>>(wq, wqkvt, 2048, 2048);
    transpose_cast<<<dim3(16, 64), dim3(32, 8), 0, stream>>>(wk, wqkvt + (size_t)2048 * 2048, 2048, 512);
    transpose_cast<<<dim3(16, 64), dim3(32, 8), 0, stream>>>(wv, wqkvt + (size_t)2560 * 2048, 2048, 512);
    transpose_cast<<<dim3(64, 64), dim3(32, 8), 0, stream>>>(wo, wot, 2048, 2048);
    gemm_bt<0><<<dim3(24, 32), 256, 0, stream>>>(xb, wqkvt, qkv, 4096, 3072, 2048);
    rope_reshape<<<4096, 256, 0, stream>>>(qkv, fc, fs, qb, kb);
    vtrans<<<dim3(16, 8), 256, 0, stream>>>(qkv, vtb);
    attn_kernel<<<dim3(16, 32), 512, 0, stream>>>(qb, kb, vtb, attno);
    gemm_bt<1><<<dim3(16, 32), 256, 0, stream>>>(attno, wot, d_out, 4096, 2048, 2048);
}